// Round 9
// baseline (623.803 us; speedup 1.0000x reference)
//
#include <hip/hip_runtime.h>

#define B_  4
#define N_  131072
#define J_  55
#define JP_ 56        // padded J (pad entries are zero)
#define D_  64
#define D3_ 262144    // 64^3
#define PF_ 486
#define COLS_ 31425   // M*3

// prelude zone sizes (blocks)
#define GZ_ 2048      // G-blend zone: 512 chunks x 4 batches (512 verts/blk)
#define OZ_ 123       // off_pose zone: one block per 256 cols, full depth

#define BL16(u) __uint_as_float((u) << 16)
#define BH16(u) __uint_as_float((u) & 0xffff0000u)

// 16B vector with only 4B alignment guarantee (lbsw rows are 220B apart)
typedef float f4a __attribute__((ext_vector_type(4), aligned(4)));

__device__ __forceinline__ unsigned short f2bf(float v) {
    unsigned u = __float_as_uint(v);
    u += 0x7fffu + ((u >> 16) & 1u);   // round-to-nearest-even
    return (unsigned short)(u >> 16);
}

// stage one batch's tfs = A@Ainv as bf16 pairs: dst[j*8+pp] packs elements
// (2pp, 2pp+1) of the 4x4 row-major matrix. 32B/joint.
__device__ __forceinline__ void stage_tfs_bf16(int b, int tid,
                                               const float* __restrict__ A,
                                               const float* __restrict__ Ainv,
                                               unsigned* __restrict__ dst) {
#pragma unroll
    for (int base = 0; base < 448; base += 256) {
        int idx = base + tid;
        if (idx < 448) {
            int j = idx >> 3, pp = idx & 7;
            float e0 = 0.f, e1 = 0.f;
            if (j < J_) {
                int r = pp >> 1, c0 = (pp & 1) * 2;   // elems 2pp,2pp+1
#pragma unroll
                for (int k = 0; k < 4; ++k) {
                    float av = A[((b * J_ + j) * 4 + r) * 4 + k];
                    e0 += av * Ainv[(j * 4 + k) * 4 + c0];
                    e1 += av * Ainv[(j * 4 + k) * 4 + c0 + 1];
                }
            }
            dst[idx] = (unsigned)f2bf(e0) | ((unsigned)f2bf(e1) << 16);
        }
    }
}

// unpack 16 bf16 (two uint4) into t[16]
#define UNP16(t, q0, q1)                                        \
    t[0]  = BL16(q0.x); t[1]  = BH16(q0.x);                     \
    t[2]  = BL16(q0.y); t[3]  = BH16(q0.y);                     \
    t[4]  = BL16(q0.z); t[5]  = BH16(q0.z);                     \
    t[6]  = BL16(q0.w); t[7]  = BH16(q0.w);                     \
    t[8]  = BL16(q1.x); t[9]  = BH16(q1.x);                     \
    t[10] = BL16(q1.y); t[11] = BH16(q1.y);                     \
    t[12] = BL16(q1.z); t[13] = BH16(q1.z);                     \
    t[14] = BL16(q1.w); t[15] = BH16(q1.w);

// ------ k_prelude: unchanged from round 8 (passed; <=91.7us) ---------------
__global__ __launch_bounds__(256) void k_prelude(
    const float* __restrict__ A, const float* __restrict__ Ainv,
    const float* __restrict__ vox,
    uint4* __restrict__ Gtb, float* __restrict__ Stb,
    const float* __restrict__ pf, const float* __restrict__ podir,
    const float* __restrict__ betas, const float* __restrict__ spdir,
    float* __restrict__ off_full) {
    int bx = blockIdx.x;
    int tid = threadIdx.x;

    if (bx < GZ_) {
        __shared__ unsigned stfsb[448];     // bf16 tfs, one batch, 1792B
        int b = (bx & 7) >> 1;
        int chunk = ((bx >> 3) << 1) | (bx & 1);   // [0,512) per b
        stage_tfs_bf16(b, tid, A, Ainv, stfsb);
        __syncthreads();

        int v0 = chunk * 512 + tid;         // this thread: v0 and v0+256
        float g0[16], g1[16];
#pragma unroll
        for (int r = 0; r < 16; ++r) { g0[r] = 0.f; g1[r] = 0.f; }
        float s0 = 0.f, s1 = 0.f;
        const uint4* s16 = (const uint4*)stfsb;
        float wa[5][2], wb[5][2];
#pragma unroll
        for (int k = 0; k < 5; ++k) {
            wa[k][0] = vox[(size_t)k * D3_ + v0];
            wa[k][1] = vox[(size_t)k * D3_ + v0 + 256];
        }
        for (int j0 = 0; j0 < J_; j0 += 5) {    // 55 = 11 x 5
            if (j0 + 5 < J_) {
#pragma unroll
                for (int k = 0; k < 5; ++k) {
                    wb[k][0] = vox[(size_t)(j0 + 5 + k) * D3_ + v0];
                    wb[k][1] = vox[(size_t)(j0 + 5 + k) * D3_ + v0 + 256];
                }
            }
#pragma unroll
            for (int k = 0; k < 5; ++k) {
                int j = j0 + k;
                uint4 q0 = s16[j * 2], q1 = s16[j * 2 + 1];
                float t[16];
                UNP16(t, q0, q1)
                float w0 = wa[k][0], w1 = wa[k][1];
                s0 += w0; s1 += w1;
#pragma unroll
                for (int r = 0; r < 16; ++r) {
                    g0[r] += w0 * t[r];
                    g1[r] += w1 * t[r];
                }
            }
#pragma unroll
            for (int k = 0; k < 5; ++k) {
                wa[k][0] = wb[k][0]; wa[k][1] = wb[k][1];
            }
        }
        if (b == 0) { Stb[v0] = s0; Stb[v0 + 256] = s1; }
#pragma unroll
        for (int m = 0; m < 2; ++m) {
            float* g = m ? g1 : g0;
            int v = v0 + m * 256;
            unsigned gw[8];
#pragma unroll
            for (int k = 0; k < 8; ++k)
                gw[k] = (unsigned)f2bf(g[2 * k]) |
                        ((unsigned)f2bf(g[2 * k + 1]) << 16);
            uint4* gp = Gtb + ((size_t)b * D3_ + v) * 2;
            gp[0] = make_uint4(gw[0], gw[1], gw[2], gw[3]);
            gp[1] = make_uint4(gw[4], gw[5], gw[6], gw[7]);
        }
    } else {
        // ---- off_pose zone: full 486 depth, 16 loads in flight
        int col = (bx - GZ_) * 256 + tid;
        if (col >= COLS_) return;
        float a0 = 0.f, a1 = 0.f, a2 = 0.f, a3 = 0.f;
        {   // shape blend term
            float sp[10];
#pragma unroll
            for (int l = 0; l < 10; ++l) sp[l] = spdir[col * 10 + l];
#pragma unroll
            for (int l = 0; l < 10; ++l) {
                a0 += betas[0 * 10 + l] * sp[l];
                a1 += betas[1 * 10 + l] * sp[l];
                a2 += betas[2 * 10 + l] * sp[l];
                a3 += betas[3 * 10 + l] * sp[l];
            }
        }
        int p = 0;
        for (; p + 16 <= PF_; p += 16) {
            float v16[16];
#pragma unroll
            for (int k = 0; k < 16; ++k)
                v16[k] = podir[(size_t)(p + k) * COLS_ + col];
#pragma unroll
            for (int k = 0; k < 16; ++k) {
                a0 += pf[0 * PF_ + p + k] * v16[k];
                a1 += pf[1 * PF_ + p + k] * v16[k];
                a2 += pf[2 * PF_ + p + k] * v16[k];
                a3 += pf[3 * PF_ + p + k] * v16[k];
            }
        }
        for (; p < PF_; ++p) {         // tail 486 - 480 = 6
            float v = podir[(size_t)p * COLS_ + col];
            a0 += pf[0 * PF_ + p] * v;
            a1 += pf[1 * PF_ + p] * v;
            a2 += pf[2 * PF_ + p] * v;
            a3 += pf[3 * PF_ + p] * v;
        }
        off_full[0 * COLS_ + col] = a0;
        off_full[1 * COLS_ + col] = a1;
        off_full[2 * COLS_ + col] = a2;
        off_full[3 * COLS_ + col] = a3;
    }
}

// accumulate 8 T-entries from two adjacent-corner G rows (bf16-packed)
#define ACC8(Toff, qa, qb)                                 \
    T[Toff + 0] += w0 * BL16(qa.x) + w1 * BL16(qb.x);      \
    T[Toff + 1] += w0 * BH16(qa.x) + w1 * BH16(qb.x);      \
    T[Toff + 2] += w0 * BL16(qa.y) + w1 * BL16(qb.y);      \
    T[Toff + 3] += w0 * BH16(qa.y) + w1 * BH16(qb.y);      \
    T[Toff + 4] += w0 * BL16(qa.z) + w1 * BL16(qb.z);      \
    T[Toff + 5] += w0 * BH16(qa.z) + w1 * BH16(qb.z);      \
    T[Toff + 6] += w0 * BL16(qa.w) + w1 * BL16(qb.w);      \
    T[Toff + 7] += w0 * BH16(qa.w) + w1 * BH16(qb.w);

// load one corner pair (rows f, f+1 = 64B) + its two S values
#define PAIRLOAD(q, sA, sB, f)                             \
    { const uint4* R = Gb + (size_t)(f) * 2;               \
      q[0] = R[0]; q[1] = R[1]; q[2] = R[2]; q[3] = R[3];  \
      sA = Stb[f]; sB = Stb[(f) + 1]; }

// consume one corner pair
#define PAIRCONS(q, sA, sB, wxy)                           \
    { float w0 = (wxy) * wz0, w1 = (wxy) * wz1;            \
      wsum += w0 * sA + w1 * sB;                           \
      uint4 q0 = q[0], q1 = q[1], q2 = q[2], q3 = q[3];    \
      ACC8(0, q0, q2) ACC8(8, q1, q3) }

// accumulate one joint from bf16 LDS tfs
#define LJACC(jj, wv)                                      \
    { uint4 a0 = s16[(jj) * 2], a1 = s16[(jj) * 2 + 1];    \
      float w = (wv); wsum += w;                           \
      T[0]  += w * BL16(a0.x); T[1]  += w * BH16(a0.x);    \
      T[2]  += w * BL16(a0.y); T[3]  += w * BH16(a0.y);    \
      T[4]  += w * BL16(a0.z); T[5]  += w * BH16(a0.z);    \
      T[6]  += w * BL16(a0.w); T[7]  += w * BH16(a0.w);    \
      T[8]  += w * BL16(a1.x); T[9]  += w * BH16(a1.x);    \
      T[10] += w * BL16(a1.y); T[11] += w * BH16(a1.y);    \
      T[12] += w * BL16(a1.z); T[13] += w * BH16(a1.z);    \
      T[14] += w * BL16(a1.w); T[15] += w * BH16(a1.w); }

// ------- fused main pass: compaction; 2-ahead pipelined paths --------------
// (256,5): cap VGPR at ~102 -> 5 blocks/CU (r8's 128 VGPR gave 16% occ;
// both paths restructured so <=2 staging groups in flight, ~85-95 natural)
__global__ __launch_bounds__(256, 5) void k_main(
    const float* __restrict__ pts, const int* __restrict__ faces,
    const float* __restrict__ poseoff, const int* __restrict__ mask,
    const float* __restrict__ vox_scale, const float* __restrict__ vox_offset,
    const float* __restrict__ off_full,
    const float* __restrict__ A, const float* __restrict__ Ainv,
    const float* __restrict__ lbsw, const uint4* __restrict__ Gtb,
    const float* __restrict__ Stb,
    float* __restrict__ out_posed, float* __restrict__ out_T) {
    __shared__ float sx0[256], sx1[256], sx2[256];
    __shared__ float sf0[256], sf1[256], sf2[256];
    __shared__ int   scell[256];
    __shared__ unsigned short lst[256];
    __shared__ int wc[4];
    __shared__ unsigned stfsb[448];      // this block's batch tfs, bf16

    // XCD binding: b = (bid&7)>>1 -> XCD pair {2b,2b+1} owns batch b.
    int bid = blockIdx.x;
    int b  = (bid & 7) >> 1;
    int nc = ((bid >> 3) << 1) | (bid & 1);     // [0,512) per b, bijective
    int tid = threadIdx.x;
    int n = nc * 256 + tid;
    int i = (b << 17) | n;

    stage_tfs_bf16(b, tid, A, Ainv, stfsb);   // done by first __syncthreads

    float px = pts[3 * i + 0], py = pts[3 * i + 1], pz = pts[3 * i + 2];
    int f0 = faces[3 * n + 0], f1 = faces[3 * n + 1], f2 = faces[3 * n + 2];
    const float* ob = off_full + b * COLS_;
    const float c3 = 1.f / 3.f;
    // 3 x f4a gathers (vs 9 scattered dwords); off_full padded, over-read ok
    f4a o0 = *(const f4a*)(ob + f0 * 3);
    f4a o1 = *(const f4a*)(ob + f1 * 3);
    f4a o2 = *(const f4a*)(ob + f2 * 3);
    float ox = (o0[0] + o1[0] + o2[0]) * c3;
    float oy = (o0[1] + o1[1] + o2[1]) * c3;
    float oz = (o0[2] + o1[2] + o2[2]) * c3;
    sx0[tid] = px + ox - poseoff[3 * n + 0];
    sx1[tid] = py + oy - poseoff[3 * n + 1];
    sx2[tid] = pz + oz - poseoff[3 * n + 2];

    bool isv = !(mask[i] > 0);
    if (isv) {
        float sxc = vox_scale[0], syc = vox_scale[1], szc = vox_scale[2];
        float q0 = vox_offset[0], q1 = vox_offset[1], q2 = vox_offset[2];
        float gx = fminf(fmaxf(px * sxc + q0, -1.f), 1.f);
        float gy = fminf(fmaxf(py * syc + q1, -1.f), 1.f);
        float gz = fminf(fmaxf(pz * szc + q2, -1.f), 1.f);
        float tx = (gx + 1.f) * 0.5f * (D_ - 1);
        float ty = (gy + 1.f) * 0.5f * (D_ - 1);
        float tz = (gz + 1.f) * 0.5f * (D_ - 1);
        int ix = (int)floorf(tx); if (ix > D_ - 2) ix = D_ - 2; if (ix < 0) ix = 0;
        int iy = (int)floorf(ty); if (iy > D_ - 2) iy = D_ - 2; if (iy < 0) iy = 0;
        int iz = (int)floorf(tz); if (iz > D_ - 2) iz = D_ - 2; if (iz < 0) iz = 0;
        sf0[tid] = tx - ix;
        sf1[tid] = ty - iy;
        sf2[tid] = tz - iz;
        scell[tid] = (ix * D_ + iy) * D_ + iz;
    }

    unsigned long long bal = __ballot(isv);
    int lane = tid & 63, wid = tid >> 6;
    if (lane == 0) wc[wid] = __popcll(bal);
    __syncthreads();
    int pre = 0;
#pragma unroll
    for (int k = 0; k < 4; ++k) pre += (k < wid) ? wc[k] : 0;
    int tot = wc[0] + wc[1] + wc[2] + wc[3];
    unsigned long long lt = ((unsigned long long)1 << lane) - 1ull;
    int vbefore = pre + __popcll(bal & lt);       // voxel threads before me
    int pos = isv ? vbefore : (tot + (tid - vbefore));
    lst[pos] = (unsigned short)tid;
    __syncthreads();

    int slot = lst[tid];
    float x0 = sx0[slot], x1 = sx1[slot], x2 = sx2[slot];
    int ii = (b << 17) | (nc * 256 + slot);

    float T[16];
#pragma unroll
    for (int r = 0; r < 16; ++r) T[r] = 0.f;
    float wsum = 0.f;

    if (tid < tot) {
        // voxel path: 4 corner pairs, 2 register sets alternating (2-ahead)
        float fx = sf0[slot], fy = sf1[slot], fz = sf2[slot];
        int cell = scell[slot];
        const uint4* Gb = Gtb + (size_t)b * D3_ * 2;
        float wz0 = 1.f - fz, wz1 = fz;
        float wxy0 = (1.f - fx) * (1.f - fy);
        float wxy1 = (1.f - fx) * fy;
        float wxy2 = fx * (1.f - fy);
        float wxy3 = fx * fy;
        int fid0 = cell;
        int fid1 = cell + D_;
        int fid2 = cell + D_ * D_;
        int fid3 = cell + D_ * D_ + D_;
        uint4 qa[4], qb[4];
        float sa0, sa1, sb0, sb1;
        PAIRLOAD(qa, sa0, sa1, fid0)
        PAIRLOAD(qb, sb0, sb1, fid1)
        PAIRCONS(qa, sa0, sa1, wxy0)
        PAIRLOAD(qa, sa0, sa1, fid2)
        PAIRCONS(qb, sb0, sb1, wxy1)
        PAIRLOAD(qb, sb0, sb1, fid3)
        PAIRCONS(qa, sa0, sa1, wxy2)
        PAIRCONS(qb, sb0, sb1, wxy3)
    } else {
        // lbsw path: 16-weight chunks, 2 chunks in flight; bf16 tfs from LDS
        int n2 = nc * 256 + slot;
        const float* lw = lbsw + (size_t)n2 * J_;
        const uint4* s16 = (const uint4*)stfsb;
        f4a qa4[4], qb4[4];
#pragma unroll
        for (int k = 0; k < 4; ++k) qa4[k] = *(const f4a*)(lw + 4 * k);
#pragma unroll
        for (int k = 0; k < 4; ++k) qb4[k] = *(const f4a*)(lw + 16 + 4 * k);
#pragma unroll
        for (int jj = 0; jj < 16; ++jj) LJACC(jj, qa4[jj >> 2][jj & 3])
#pragma unroll
        for (int k = 0; k < 4; ++k) qa4[k] = *(const f4a*)(lw + 32 + 4 * k);
#pragma unroll
        for (int jj = 16; jj < 32; ++jj)
            LJACC(jj, qb4[(jj - 16) >> 2][(jj - 16) & 3])
        f4a qt = *(const f4a*)(lw + 48);
        float w52 = lw[52], w53 = lw[53], w54 = lw[54];
#pragma unroll
        for (int jj = 32; jj < 48; ++jj)
            LJACC(jj, qa4[(jj - 32) >> 2][(jj - 32) & 3])
#pragma unroll
        for (int jj = 48; jj < 52; ++jj) LJACC(jj, qt[jj - 48])
        LJACC(52, w52)
        LJACC(53, w53)
        LJACC(54, w54)
    }

    float inv = 1.f / fmaxf(wsum, 1e-8f);
    float t[16];
#pragma unroll
    for (int r = 0; r < 16; ++r) t[r] = T[r] * inv;
    // regular cached stores: block covers a contiguous region; L2 write-back
    // evicts full lines
    out_posed[3 * ii + 0] = t[0] * x0 + t[1] * x1 + t[2] * x2 + t[3];
    out_posed[3 * ii + 1] = t[4] * x0 + t[5] * x1 + t[6] * x2 + t[7];
    out_posed[3 * ii + 2] = t[8] * x0 + t[9] * x1 + t[10] * x2 + t[11];
    float4* to = (float4*)(out_T + (size_t)ii * 16);
    to[0] = make_float4(t[0], t[1], t[2], t[3]);
    to[1] = make_float4(t[4], t[5], t[6], t[7]);
    to[2] = make_float4(t[8], t[9], t[10], t[11]);
    to[3] = make_float4(t[12], t[13], t[14], t[15]);
}

extern "C" void kernel_launch(void* const* d_in, const int* in_sizes, int n_in,
                              void* d_out, int out_size, void* d_ws, size_t ws_size,
                              hipStream_t stream) {
    const float* pts      = (const float*)d_in[0];
    const float* betas    = (const float*)d_in[1];
    const float* pf       = (const float*)d_in[2];
    const float* spdir    = (const float*)d_in[3];
    const float* podir    = (const float*)d_in[4];
    const int*   faces    = (const int*)d_in[5];
    const float* tfs_A    = (const float*)d_in[6];
    const float* tfs_inv  = (const float*)d_in[7];
    const float* poseoff  = (const float*)d_in[8];
    const float* lbsw     = (const float*)d_in[9];
    const float* vox      = (const float*)d_in[10];
    const float* vscale   = (const float*)d_in[11];
    const float* voffset  = (const float*)d_in[12];
    const int*   mask     = (const int*)d_in[13];

    // workspace layout (256B-aligned)
    char* w = (char*)d_ws;
    uint4* Gtb      = (uint4*)w;                       // 33,554,432 B
    float* Stb      = (float*)(w + 33554432);          //  1,048,576 B
    float* off_full = (float*)(w + 34603008);          //    516,096 B (padded)
    // total: 35,119,104 B

    float* out_posed = (float*)d_out;
    float* out_T     = out_posed + (size_t)B_ * N_ * 3;

    k_prelude<<<GZ_ + OZ_, 256, 0, stream>>>(
        tfs_A, tfs_inv, vox, Gtb, Stb, pf, podir, betas, spdir, off_full);
    k_main<<<2048, 256, 0, stream>>>(pts, faces, poseoff, mask, vscale,
                                     voffset, off_full, tfs_A, tfs_inv,
                                     lbsw, Gtb, Stb, out_posed, out_T);
}

// Round 10
// 277.159 us; speedup vs baseline: 2.2507x; 2.2507x over previous
//
#include <hip/hip_runtime.h>

#define B_  4
#define N_  131072
#define J_  55
#define JP_ 56        // padded J (pad entries are zero)
#define D_  64
#define D3_ 262144    // 64^3
#define PF_ 486
#define COLS_ 31425   // M*3

// prelude zone sizes (blocks)
#define GZ_ 2048      // G-blend zone: 512 chunks x 4 batches (512 verts/blk)
#define OZ_ 123       // off_pose zone: one block per 256 cols, full depth
#define PZ_ 14336     // lbsw pack zone: N_*28/256

#define BL16(u) __uint_as_float((u) << 16)
#define BH16(u) __uint_as_float((u) & 0xffff0000u)

// 16B vector with only 4B alignment guarantee
typedef float f4a __attribute__((ext_vector_type(4), aligned(4)));

__device__ __forceinline__ unsigned short f2bf(float v) {
    unsigned u = __float_as_uint(v);
    u += 0x7fffu + ((u >> 16) & 1u);   // round-to-nearest-even
    return (unsigned short)(u >> 16);
}

// stage one batch's tfs = A@Ainv as bf16 pairs: dst[j*8+pp] packs elements
// (2pp, 2pp+1) of the 4x4 row-major matrix. 32B/joint.
__device__ __forceinline__ void stage_tfs_bf16(int b, int tid,
                                               const float* __restrict__ A,
                                               const float* __restrict__ Ainv,
                                               unsigned* __restrict__ dst) {
#pragma unroll
    for (int base = 0; base < 448; base += 256) {
        int idx = base + tid;
        if (idx < 448) {
            int j = idx >> 3, pp = idx & 7;
            float e0 = 0.f, e1 = 0.f;
            if (j < J_) {
                int r = pp >> 1, c0 = (pp & 1) * 2;   // elems 2pp,2pp+1
#pragma unroll
                for (int k = 0; k < 4; ++k) {
                    float av = A[((b * J_ + j) * 4 + r) * 4 + k];
                    e0 += av * Ainv[(j * 4 + k) * 4 + c0];
                    e1 += av * Ainv[(j * 4 + k) * 4 + c0 + 1];
                }
            }
            dst[idx] = (unsigned)f2bf(e0) | ((unsigned)f2bf(e1) << 16);
        }
    }
}

// unpack 16 bf16 (two uint4) into t[16]
#define UNP16(t, q0, q1)                                        \
    t[0]  = BL16(q0.x); t[1]  = BH16(q0.x);                     \
    t[2]  = BL16(q0.y); t[3]  = BH16(q0.y);                     \
    t[4]  = BL16(q0.z); t[5]  = BH16(q0.z);                     \
    t[6]  = BL16(q0.w); t[7]  = BH16(q0.w);                     \
    t[8]  = BL16(q1.x); t[9]  = BH16(q1.x);                     \
    t[10] = BL16(q1.y); t[11] = BH16(q1.y);                     \
    t[12] = BL16(q1.z); t[13] = BH16(q1.z);                     \
    t[14] = BL16(q1.w); t[15] = BH16(q1.w);

// ------ k_prelude: three independent zones overlap on the GPU --------------
// zone G [0,GZ_):            G[b][v][16] bf16 + S[v] f32 (as round 8)
// zone O [GZ_,GZ_+OZ_):      off_full = betas@spdir + pf@podir
// zone P [GZ_+OZ_, +PZ_):    pack lbsw f32[N][55] -> bf16[N][56] (112B rows;
//                            k_main then issues 7 ALIGNED dwordx4 instead of
//                            13 unaligned f4a that split into 26 requests —
//                            the feature that made r2's k_main 82.9us)
__global__ __launch_bounds__(256) void k_prelude(
    const float* __restrict__ A, const float* __restrict__ Ainv,
    const float* __restrict__ vox,
    uint4* __restrict__ Gtb, float* __restrict__ Stb,
    const float* __restrict__ pf, const float* __restrict__ podir,
    const float* __restrict__ betas, const float* __restrict__ spdir,
    float* __restrict__ off_full,
    const float* __restrict__ lbsw, unsigned* __restrict__ lbswP32) {
    int bx = blockIdx.x;
    int tid = threadIdx.x;

    if (bx < GZ_) {
        __shared__ unsigned stfsb[448];     // bf16 tfs, one batch, 1792B
        int b = (bx & 7) >> 1;
        int chunk = ((bx >> 3) << 1) | (bx & 1);   // [0,512) per b
        stage_tfs_bf16(b, tid, A, Ainv, stfsb);
        __syncthreads();

        int v0 = chunk * 512 + tid;         // this thread: v0 and v0+256
        float g0[16], g1[16];
#pragma unroll
        for (int r = 0; r < 16; ++r) { g0[r] = 0.f; g1[r] = 0.f; }
        float s0 = 0.f, s1 = 0.f;
        const uint4* s16 = (const uint4*)stfsb;
        float wa[5][2], wb[5][2];
#pragma unroll
        for (int k = 0; k < 5; ++k) {
            wa[k][0] = vox[(size_t)k * D3_ + v0];
            wa[k][1] = vox[(size_t)k * D3_ + v0 + 256];
        }
        for (int j0 = 0; j0 < J_; j0 += 5) {    // 55 = 11 x 5
            if (j0 + 5 < J_) {
#pragma unroll
                for (int k = 0; k < 5; ++k) {
                    wb[k][0] = vox[(size_t)(j0 + 5 + k) * D3_ + v0];
                    wb[k][1] = vox[(size_t)(j0 + 5 + k) * D3_ + v0 + 256];
                }
            }
#pragma unroll
            for (int k = 0; k < 5; ++k) {
                int j = j0 + k;
                uint4 q0 = s16[j * 2], q1 = s16[j * 2 + 1];
                float t[16];
                UNP16(t, q0, q1)
                float w0 = wa[k][0], w1 = wa[k][1];
                s0 += w0; s1 += w1;
#pragma unroll
                for (int r = 0; r < 16; ++r) {
                    g0[r] += w0 * t[r];
                    g1[r] += w1 * t[r];
                }
            }
#pragma unroll
            for (int k = 0; k < 5; ++k) {
                wa[k][0] = wb[k][0]; wa[k][1] = wb[k][1];
            }
        }
        if (b == 0) { Stb[v0] = s0; Stb[v0 + 256] = s1; }
#pragma unroll
        for (int m = 0; m < 2; ++m) {
            float* g = m ? g1 : g0;
            int v = v0 + m * 256;
            unsigned gw[8];
#pragma unroll
            for (int k = 0; k < 8; ++k)
                gw[k] = (unsigned)f2bf(g[2 * k]) |
                        ((unsigned)f2bf(g[2 * k + 1]) << 16);
            uint4* gp = Gtb + ((size_t)b * D3_ + v) * 2;
            gp[0] = make_uint4(gw[0], gw[1], gw[2], gw[3]);
            gp[1] = make_uint4(gw[4], gw[5], gw[6], gw[7]);
        }
    } else if (bx < GZ_ + OZ_) {
        // ---- off_pose zone: full 486 depth, 16 loads in flight
        int col = (bx - GZ_) * 256 + tid;
        if (col >= COLS_) return;
        float a0 = 0.f, a1 = 0.f, a2 = 0.f, a3 = 0.f;
        {   // shape blend term
            float sp[10];
#pragma unroll
            for (int l = 0; l < 10; ++l) sp[l] = spdir[col * 10 + l];
#pragma unroll
            for (int l = 0; l < 10; ++l) {
                a0 += betas[0 * 10 + l] * sp[l];
                a1 += betas[1 * 10 + l] * sp[l];
                a2 += betas[2 * 10 + l] * sp[l];
                a3 += betas[3 * 10 + l] * sp[l];
            }
        }
        int p = 0;
        for (; p + 16 <= PF_; p += 16) {
            float v16[16];
#pragma unroll
            for (int k = 0; k < 16; ++k)
                v16[k] = podir[(size_t)(p + k) * COLS_ + col];
#pragma unroll
            for (int k = 0; k < 16; ++k) {
                a0 += pf[0 * PF_ + p + k] * v16[k];
                a1 += pf[1 * PF_ + p + k] * v16[k];
                a2 += pf[2 * PF_ + p + k] * v16[k];
                a3 += pf[3 * PF_ + p + k] * v16[k];
            }
        }
        for (; p < PF_; ++p) {         // tail 486 - 480 = 6
            float v = podir[(size_t)p * COLS_ + col];
            a0 += pf[0 * PF_ + p] * v;
            a1 += pf[1 * PF_ + p] * v;
            a2 += pf[2 * PF_ + p] * v;
            a3 += pf[3 * PF_ + p] * v;
        }
        off_full[0 * COLS_ + col] = a0;
        off_full[1 * COLS_ + col] = a1;
        off_full[2 * COLS_ + col] = a2;
        off_full[3 * COLS_ + col] = a3;
    } else {
        // ---- pack zone: element e -> row n = e/28, word jj = e%28
        int e = (bx - GZ_ - OZ_) * 256 + tid;     // PZ_*256 == N_*28 exactly
        int n = e / 28;
        int jj = e - n * 28;
        int j0 = 2 * jj;
        float w0 = lbsw[(size_t)n * J_ + j0];
        float w1 = (j0 + 1 < J_) ? lbsw[(size_t)n * J_ + j0 + 1] : 0.f;
        lbswP32[e] = (unsigned)f2bf(w0) | ((unsigned)f2bf(w1) << 16);
    }
}

// accumulate 8 T-entries from two adjacent-corner G rows (bf16-packed)
#define ACC8(Toff, qa, qb)                                 \
    T[Toff + 0] += w0 * BL16(qa.x) + w1 * BL16(qb.x);      \
    T[Toff + 1] += w0 * BH16(qa.x) + w1 * BH16(qb.x);      \
    T[Toff + 2] += w0 * BL16(qa.y) + w1 * BL16(qb.y);      \
    T[Toff + 3] += w0 * BH16(qa.y) + w1 * BH16(qb.y);      \
    T[Toff + 4] += w0 * BL16(qa.z) + w1 * BL16(qb.z);      \
    T[Toff + 5] += w0 * BH16(qa.z) + w1 * BH16(qb.z);      \
    T[Toff + 6] += w0 * BL16(qa.w) + w1 * BL16(qb.w);      \
    T[Toff + 7] += w0 * BH16(qa.w) + w1 * BH16(qb.w);

// load one corner pair (rows f, f+1 = 64B) + its two S values
#define PAIRLOAD(q, sA, sB, f)                             \
    { const uint4* R = Gb + (size_t)(f) * 2;               \
      q[0] = R[0]; q[1] = R[1]; q[2] = R[2]; q[3] = R[3];  \
      sA = Stb[f]; sB = Stb[(f) + 1]; }

// consume one corner pair
#define PAIRCONS(q, sA, sB, wxy)                           \
    { float w0 = (wxy) * wz0, w1 = (wxy) * wz1;            \
      wsum += w0 * sA + w1 * sB;                           \
      uint4 q0 = q[0], q1 = q[1], q2 = q[2], q3 = q[3];    \
      ACC8(0, q0, q2) ACC8(8, q1, q3) }

// accumulate one joint from bf16 LDS tfs
#define LJACC(jj, wv)                                      \
    { uint4 a0 = s16[(jj) * 2], a1 = s16[(jj) * 2 + 1];    \
      float w = (wv); wsum += w;                           \
      T[0]  += w * BL16(a0.x); T[1]  += w * BH16(a0.x);    \
      T[2]  += w * BL16(a0.y); T[3]  += w * BH16(a0.y);    \
      T[4]  += w * BL16(a0.z); T[5]  += w * BH16(a0.z);    \
      T[6]  += w * BL16(a0.w); T[7]  += w * BH16(a0.w);    \
      T[8]  += w * BL16(a1.x); T[9]  += w * BH16(a1.x);    \
      T[10] += w * BL16(a1.y); T[11] += w * BH16(a1.y);    \
      T[12] += w * BL16(a1.z); T[13] += w * BH16(a1.z);    \
      T[14] += w * BL16(a1.w); T[15] += w * BH16(a1.w); }

// ------- fused main pass: compaction; 2-ahead voxel pipe; packed lbsw ------
// plain __launch_bounds__(256): r9's (256,5) forced VGPR to 48 -> scratch
// spill (WRITE 716MB, 455us). Let the allocator pick (~90-100 expected).
__global__ __launch_bounds__(256) void k_main(
    const float* __restrict__ pts, const int* __restrict__ faces,
    const float* __restrict__ poseoff, const int* __restrict__ mask,
    const float* __restrict__ vox_scale, const float* __restrict__ vox_offset,
    const float* __restrict__ off_full,
    const float* __restrict__ A, const float* __restrict__ Ainv,
    const unsigned short* __restrict__ lbswP, const uint4* __restrict__ Gtb,
    const float* __restrict__ Stb,
    float* __restrict__ out_posed, float* __restrict__ out_T) {
    __shared__ float sx0[256], sx1[256], sx2[256];
    __shared__ float sf0[256], sf1[256], sf2[256];
    __shared__ int   scell[256];
    __shared__ unsigned short lst[256];
    __shared__ int wc[4];
    __shared__ unsigned stfsb[448];      // this block's batch tfs, bf16

    // XCD binding: b = (bid&7)>>1 -> XCD pair {2b,2b+1} owns batch b.
    int bid = blockIdx.x;
    int b  = (bid & 7) >> 1;
    int nc = ((bid >> 3) << 1) | (bid & 1);     // [0,512) per b, bijective
    int tid = threadIdx.x;
    int n = nc * 256 + tid;
    int i = (b << 17) | n;

    stage_tfs_bf16(b, tid, A, Ainv, stfsb);   // done by first __syncthreads

    float px = pts[3 * i + 0], py = pts[3 * i + 1], pz = pts[3 * i + 2];
    int f0 = faces[3 * n + 0], f1 = faces[3 * n + 1], f2 = faces[3 * n + 2];
    const float* ob = off_full + b * COLS_;
    const float c3 = 1.f / 3.f;
    // 3 x f4a gathers (vs 9 scattered dwords); off_full padded, over-read ok
    f4a o0 = *(const f4a*)(ob + f0 * 3);
    f4a o1 = *(const f4a*)(ob + f1 * 3);
    f4a o2 = *(const f4a*)(ob + f2 * 3);
    float ox = (o0[0] + o1[0] + o2[0]) * c3;
    float oy = (o0[1] + o1[1] + o2[1]) * c3;
    float oz = (o0[2] + o1[2] + o2[2]) * c3;
    sx0[tid] = px + ox - poseoff[3 * n + 0];
    sx1[tid] = py + oy - poseoff[3 * n + 1];
    sx2[tid] = pz + oz - poseoff[3 * n + 2];

    bool isv = !(mask[i] > 0);
    if (isv) {
        float sxc = vox_scale[0], syc = vox_scale[1], szc = vox_scale[2];
        float q0 = vox_offset[0], q1 = vox_offset[1], q2 = vox_offset[2];
        float gx = fminf(fmaxf(px * sxc + q0, -1.f), 1.f);
        float gy = fminf(fmaxf(py * syc + q1, -1.f), 1.f);
        float gz = fminf(fmaxf(pz * szc + q2, -1.f), 1.f);
        float tx = (gx + 1.f) * 0.5f * (D_ - 1);
        float ty = (gy + 1.f) * 0.5f * (D_ - 1);
        float tz = (gz + 1.f) * 0.5f * (D_ - 1);
        int ix = (int)floorf(tx); if (ix > D_ - 2) ix = D_ - 2; if (ix < 0) ix = 0;
        int iy = (int)floorf(ty); if (iy > D_ - 2) iy = D_ - 2; if (iy < 0) iy = 0;
        int iz = (int)floorf(tz); if (iz > D_ - 2) iz = D_ - 2; if (iz < 0) iz = 0;
        sf0[tid] = tx - ix;
        sf1[tid] = ty - iy;
        sf2[tid] = tz - iz;
        scell[tid] = (ix * D_ + iy) * D_ + iz;
    }

    unsigned long long bal = __ballot(isv);
    int lane = tid & 63, wid = tid >> 6;
    if (lane == 0) wc[wid] = __popcll(bal);
    __syncthreads();
    int pre = 0;
#pragma unroll
    for (int k = 0; k < 4; ++k) pre += (k < wid) ? wc[k] : 0;
    int tot = wc[0] + wc[1] + wc[2] + wc[3];
    unsigned long long lt = ((unsigned long long)1 << lane) - 1ull;
    int vbefore = pre + __popcll(bal & lt);       // voxel threads before me
    int pos = isv ? vbefore : (tot + (tid - vbefore));
    lst[pos] = (unsigned short)tid;
    __syncthreads();

    int slot = lst[tid];
    float x0 = sx0[slot], x1 = sx1[slot], x2 = sx2[slot];
    int ii = (b << 17) | (nc * 256 + slot);

    float T[16];
#pragma unroll
    for (int r = 0; r < 16; ++r) T[r] = 0.f;
    float wsum = 0.f;

    if (tid < tot) {
        // voxel path: 4 corner pairs, 2 register sets alternating (2-ahead)
        float fx = sf0[slot], fy = sf1[slot], fz = sf2[slot];
        int cell = scell[slot];
        const uint4* Gb = Gtb + (size_t)b * D3_ * 2;
        float wz0 = 1.f - fz, wz1 = fz;
        float wxy0 = (1.f - fx) * (1.f - fy);
        float wxy1 = (1.f - fx) * fy;
        float wxy2 = fx * (1.f - fy);
        float wxy3 = fx * fy;
        int fid0 = cell;
        int fid1 = cell + D_;
        int fid2 = cell + D_ * D_;
        int fid3 = cell + D_ * D_ + D_;
        uint4 qa[4], qb[4];
        float sa0, sa1, sb0, sb1;
        PAIRLOAD(qa, sa0, sa1, fid0)
        PAIRLOAD(qb, sb0, sb1, fid1)
        PAIRCONS(qa, sa0, sa1, wxy0)
        PAIRLOAD(qa, sa0, sa1, fid2)
        PAIRCONS(qb, sb0, sb1, wxy1)
        PAIRLOAD(qb, sb0, sb1, fid3)
        PAIRCONS(qa, sa0, sa1, wxy2)
        PAIRCONS(qb, sb0, sb1, wxy3)
    } else {
        // lbsw path: 7 ALIGNED uint4 of packed bf16 weights (112B row, one
        // vmcnt chain, 7 requests); tfs rows from bf16 LDS
        int n2 = nc * 256 + slot;
        const uint4* lwp = (const uint4*)(lbswP + (size_t)n2 * 56);
        uint4 q[7];
#pragma unroll
        for (int k = 0; k < 7; ++k) q[k] = lwp[k];
        const uint4* s16 = (const uint4*)stfsb;
#pragma unroll
        for (int k = 0; k < 7; ++k) {
            float w8[8];
            w8[0] = BL16(q[k].x); w8[1] = BH16(q[k].x);
            w8[2] = BL16(q[k].y); w8[3] = BH16(q[k].y);
            w8[4] = BL16(q[k].z); w8[5] = BH16(q[k].z);
            w8[6] = BL16(q[k].w); w8[7] = BH16(q[k].w);
#pragma unroll
            for (int m = 0; m < 8; ++m) {
                // j = 8k+m; j==55 slot: weight pad 0 and tfs row 55 is zero
                LJACC(k * 8 + m, w8[m])
            }
        }
    }

    float inv = 1.f / fmaxf(wsum, 1e-8f);
    float t[16];
#pragma unroll
    for (int r = 0; r < 16; ++r) t[r] = T[r] * inv;
    // regular cached stores: block covers a contiguous region; L2 write-back
    // evicts full lines
    out_posed[3 * ii + 0] = t[0] * x0 + t[1] * x1 + t[2] * x2 + t[3];
    out_posed[3 * ii + 1] = t[4] * x0 + t[5] * x1 + t[6] * x2 + t[7];
    out_posed[3 * ii + 2] = t[8] * x0 + t[9] * x1 + t[10] * x2 + t[11];
    float4* to = (float4*)(out_T + (size_t)ii * 16);
    to[0] = make_float4(t[0], t[1], t[2], t[3]);
    to[1] = make_float4(t[4], t[5], t[6], t[7]);
    to[2] = make_float4(t[8], t[9], t[10], t[11]);
    to[3] = make_float4(t[12], t[13], t[14], t[15]);
}

extern "C" void kernel_launch(void* const* d_in, const int* in_sizes, int n_in,
                              void* d_out, int out_size, void* d_ws, size_t ws_size,
                              hipStream_t stream) {
    const float* pts      = (const float*)d_in[0];
    const float* betas    = (const float*)d_in[1];
    const float* pf       = (const float*)d_in[2];
    const float* spdir    = (const float*)d_in[3];
    const float* podir    = (const float*)d_in[4];
    const int*   faces    = (const int*)d_in[5];
    const float* tfs_A    = (const float*)d_in[6];
    const float* tfs_inv  = (const float*)d_in[7];
    const float* poseoff  = (const float*)d_in[8];
    const float* lbsw     = (const float*)d_in[9];
    const float* vox      = (const float*)d_in[10];
    const float* vscale   = (const float*)d_in[11];
    const float* voffset  = (const float*)d_in[12];
    const int*   mask     = (const int*)d_in[13];

    // workspace layout (256B-aligned)
    char* w = (char*)d_ws;
    uint4* Gtb            = (uint4*)w;                       // 33,554,432 B
    float* Stb            = (float*)(w + 33554432);          //  1,048,576 B
    unsigned short* lbswP = (unsigned short*)(w + 34603008); // 14,680,064 B
    float* off_full       = (float*)(w + 49283072);          //    516,096 B
    // total: 49,799,168 B

    float* out_posed = (float*)d_out;
    float* out_T     = out_posed + (size_t)B_ * N_ * 3;

    k_prelude<<<GZ_ + OZ_ + PZ_, 256, 0, stream>>>(
        tfs_A, tfs_inv, vox, Gtb, Stb, pf, podir, betas, spdir, off_full,
        lbsw, (unsigned*)lbswP);
    k_main<<<2048, 256, 0, stream>>>(pts, faces, poseoff, mask, vscale,
                                     voffset, off_full, tfs_A, tfs_inv,
                                     lbswP, Gtb, Stb, out_posed, out_T);
}